// Round 4
// baseline (136.874 us; speedup 1.0000x reference)
//
#include <hip/hip_runtime.h>
#include <hip/hip_bf16.h>

typedef __attribute__((ext_vector_type(8))) short bf16x8;
typedef __attribute__((ext_vector_type(4))) float f32x4;

#define B_ROWS 8192
#define NROWS 16384             // 2B
#define D 128
#define C1 2.8853900817779268f  // 2*log2(e)  (sim = 2*cos; exp(x)=2^(x*log2e))
#define E_M2 0.13533528323661270f // exp(-2) == 2^(-C1): the folded row-max shift
#define RSCALE 1.6986436f       // sqrt(C1), folded into reps on both operands
#define JSPLIT 8
#define COLS (NROWS / JSPLIT)   // 2048 columns per block
#define NBATCH (COLS / 64)      // 32 batches of 4 col-tiles

// Raw hardware exp2/log2: args are bounded, no range handling needed.
__device__ __forceinline__ float fast_exp2(float x) {
#if __has_builtin(__builtin_amdgcn_exp2f)
    return __builtin_amdgcn_exp2f(x);
#else
    float r; asm("v_exp_f32 %0, %1" : "=v"(r) : "v"(x)); return r;
#endif
}
__device__ __forceinline__ float fast_log2(float x) {
#if __has_builtin(__builtin_amdgcn_logf)
    return __builtin_amdgcn_logf(x);
#else
    float r; asm("v_log_f32 %0, %1" : "=v"(r) : "v"(x)); return r;
#endif
}

__device__ __forceinline__ unsigned short f2bf(float f) {
    union { float f; unsigned u; } v; v.f = f;
    unsigned r = v.u + 0x7FFFu + ((v.u >> 16) & 1u); // RNE
    return (unsigned short)(r >> 16);
}

// K1: row norms + positive dots + bf16 reps (pre-scaled by sqrt(C1)).
__global__ __launch_bounds__(256) void k_norm(const float* __restrict__ zi,
                                              const float* __restrict__ zj,
                                              unsigned* __restrict__ repsU,
                                              float* __restrict__ pos) {
    int w = threadIdx.x >> 6, lane = threadIdx.x & 63;
    int row = blockIdx.x * 4 + w;
    const float2* a2 = (const float2*)(zi + (size_t)row * D);
    const float2* b2 = (const float2*)(zj + (size_t)row * D);
    float2 a = a2[lane], b = b2[lane];
    float si = a.x * a.x + a.y * a.y;
    float sj = b.x * b.x + b.y * b.y;
    float sd = a.x * b.x + a.y * b.y;
#pragma unroll
    for (int m = 32; m; m >>= 1) {
        si += __shfl_xor(si, m);
        sj += __shfl_xor(sj, m);
        sd += __shfl_xor(sd, m);
    }
    float inv_i = 1.0f / fmaxf(sqrtf(si), 1e-12f);
    float inv_j = 1.0f / fmaxf(sqrtf(sj), 1e-12f);
    float sa = inv_i * RSCALE, sb = inv_j * RSCALE;
    repsU[(size_t)row * 64 + lane] =
        (unsigned)f2bf(a.x * sa) | ((unsigned)f2bf(a.y * sa) << 16);
    repsU[(size_t)(row + B_ROWS) * 64 + lane] =
        (unsigned)f2bf(b.x * sb) | ((unsigned)f2bf(b.y * sb) << 16);
    if (lane == 0) pos[row] = fast_exp2(sd * inv_i * inv_j * C1); // exp(2*cos_ij)
}

// K2: fused sim-GEMM + exp + row-sum. 4 waves x 64 rows, 2048-col partition.
// Batch of 4 col-tiles per iteration: 16 dwordx4 loads in flight, then
// 64 MFMA + 64 exp2-add — amortizes L2 latency 4x vs per-tile loop.
// Diagonal batch (t == tdiag) is identified wave-uniformly; inside it the
// masked sub-tile is exactly ct==r (compile-time), so the hot path has
// zero per-subtile branches.
// C/D layout (m89-verified): row=(lane>>4)*4+q, col=lane&15.
__global__ __launch_bounds__(256, 2) void k_negsum(const unsigned short* __restrict__ R,
                                                   float* __restrict__ partial) {
    int js = blockIdx.x & (JSPLIT - 1);     // low bits -> js == XCD id (L2 locality)
    int rowBase = (blockIdx.x >> 3) * 256;
    int w = threadIdx.x >> 6;
    int lane = threadIdx.x & 63;
    int lr = lane & 15, lk = lane >> 4;
    int waveRow = rowBase + w * 64;

    bf16x8 afrag[4][4];
#pragma unroll
    for (int r = 0; r < 4; ++r)
#pragma unroll
        for (int kk = 0; kk < 4; ++kk)
            afrag[r][kk] = *(const bf16x8*)(R + (size_t)(waveRow + r * 16 + lr) * D + kk * 32 + lk * 8);

    float acc[4][4] = {};
    int colStart = js * COLS;
    int tdiag = (waveRow - colStart) >> 6;  // batch containing the diagonal (if in [0,32))

#define BATCH_BODY(DIAG)                                                          \
    do {                                                                          \
        _Pragma("unroll")                                                         \
        for (int ct = 0; ct < 4; ++ct) {                                          \
            _Pragma("unroll")                                                     \
            for (int r = 0; r < 4; ++r) {                                         \
                f32x4 c = {0.f, 0.f, 0.f, 0.f};                                   \
                c = __builtin_amdgcn_mfma_f32_16x16x32_bf16(afrag[r][0], bf[ct][0], c, 0, 0, 0); \
                c = __builtin_amdgcn_mfma_f32_16x16x32_bf16(afrag[r][1], bf[ct][1], c, 0, 0, 0); \
                c = __builtin_amdgcn_mfma_f32_16x16x32_bf16(afrag[r][2], bf[ct][2], c, 0, 0, 0); \
                c = __builtin_amdgcn_mfma_f32_16x16x32_bf16(afrag[r][3], bf[ct][3], c, 0, 0, 0); \
                if (DIAG && ct == r) {                                            \
                    _Pragma("unroll")                                             \
                    for (int q = 0; q < 4; ++q)                                   \
                        if (lk * 4 + q != lr) acc[r][q] += fast_exp2(c[q]);       \
                } else {                                                          \
                    _Pragma("unroll")                                             \
                    for (int q = 0; q < 4; ++q) acc[r][q] += fast_exp2(c[q]);     \
                }                                                                 \
            }                                                                     \
        }                                                                         \
    } while (0)

    for (int t = 0; t < NBATCH; ++t) {
        const unsigned short* bp = R + (size_t)(colStart + t * 64 + lr) * D + lk * 8;
        bf16x8 bf[4][4];
#pragma unroll
        for (int ct = 0; ct < 4; ++ct)
#pragma unroll
            for (int kk = 0; kk < 4; ++kk)
                bf[ct][kk] = *(const bf16x8*)(bp + ct * 16 * D + kk * 32);
        if (t == tdiag) {
            BATCH_BODY(true);
        } else {
            BATCH_BODY(false);
        }
    }
#undef BATCH_BODY

    // reduce the 16 col-lanes of each row group, write deterministic partials
#pragma unroll
    for (int r = 0; r < 4; ++r)
#pragma unroll
        for (int q = 0; q < 4; ++q) {
            float v = acc[r][q];
            v += __shfl_xor(v, 1);
            v += __shfl_xor(v, 2);
            v += __shfl_xor(v, 4);
            v += __shfl_xor(v, 8);
            if (lr == 0)
                partial[(size_t)js * NROWS + waveRow + r * 16 + lk * 4 + q] = v;
        }
}

// K3a: per-row loss terms + block partial sums. 64 blocks x 256 threads.
__global__ __launch_bounds__(256) void k_loss1(const float* __restrict__ pos,
                                               const float* __restrict__ partial,
                                               float* __restrict__ bsum) {
    int i = blockIdx.x * 256 + threadIdx.x;
    float neg = 0.f;
#pragma unroll
    for (int s = 0; s < JSPLIT; ++s) neg += partial[(size_t)s * NROWS + i];
    neg *= E_M2; // folded (sim - 2.0) shift
    float p = pos[i & (B_ROWS - 1)];
    float Ng = fmaxf((neg - 819.2f * p) * (1.0f / 0.9f), 8192.0f * E_M2);
    float l = fast_log2((p + Ng + 1e-8f) / p) * 0.69314718056f; // = -log(p/(p+Ng+eps))
#pragma unroll
    for (int m = 32; m; m >>= 1) l += __shfl_xor(l, m);
    __shared__ float s4[4];
    int wv = threadIdx.x >> 6;
    if ((threadIdx.x & 63) == 0) s4[wv] = l;
    __syncthreads();
    if (threadIdx.x == 0) bsum[blockIdx.x] = s4[0] + s4[1] + s4[2] + s4[3];
}

// K3b: final reduce of 64 block sums. 1 block, 1 wave.
__global__ void k_loss2(const float* __restrict__ bsum, float* __restrict__ out) {
    float v = bsum[threadIdx.x];
#pragma unroll
    for (int m = 32; m; m >>= 1) v += __shfl_xor(v, m);
    if (threadIdx.x == 0) out[0] = v * (1.0f / (float)NROWS);
}

extern "C" void kernel_launch(void* const* d_in, const int* in_sizes, int n_in,
                              void* d_out, int out_size, void* d_ws, size_t ws_size,
                              hipStream_t stream) {
    const float* zi = (const float*)d_in[0];
    const float* zj = (const float*)d_in[1];
    unsigned short* reps = (unsigned short*)d_ws;                    // 16384*128 bf16 = 4 MB
    float* pos = (float*)((char*)d_ws + (size_t)NROWS * D * 2);      // 8192 f32
    float* partial = pos + B_ROWS;                                   // 8*16384 f32
    float* bsum = partial + (size_t)JSPLIT * NROWS;                  // 64 f32
    float* out = (float*)d_out;

    k_norm<<<B_ROWS / 4, 256, 0, stream>>>(zi, zj, (unsigned*)reps, pos);
    k_negsum<<<64 * JSPLIT, 256, 0, stream>>>(reps, partial);
    k_loss1<<<NROWS / 256, 256, 0, stream>>>(pos, partial, bsum);
    k_loss2<<<1, 64, 0, stream>>>(bsum, out);
}

// Round 5
// 78.778 us; speedup vs baseline: 1.7375x; 1.7375x over previous
//
#include <hip/hip_runtime.h>
#include <hip/hip_bf16.h>

typedef __attribute__((ext_vector_type(8))) short bf16x8;
typedef __attribute__((ext_vector_type(4))) float f32x4;

#define B_ROWS 8192
#define NROWS 16384             // 2B
#define D 128
#define C1 2.8853900817779268f  // 2*log2(e)  (sim = 2*cos; exp(x)=2^(x*log2e))
#define E_M2 0.13533528323661270f // exp(-2) == 2^(-C1): the folded row-max shift
#define RSCALE 1.6986436f       // sqrt(C1), folded into reps on both operands
#define JSPLIT 8
#define COLS (NROWS / JSPLIT)   // 2048 columns per block
#define TILE_COLS 64
#define TILE_BYTES (TILE_COLS * D * 2) // 16 KB per buffer
#define NT (COLS / TILE_COLS)   // 32 tiles

// Raw hardware exp2/log2: args are bounded, no range handling needed.
__device__ __forceinline__ float fast_exp2(float x) {
#if __has_builtin(__builtin_amdgcn_exp2f)
    return __builtin_amdgcn_exp2f(x);
#else
    float r; asm("v_exp_f32 %0, %1" : "=v"(r) : "v"(x)); return r;
#endif
}
__device__ __forceinline__ float fast_log2(float x) {
#if __has_builtin(__builtin_amdgcn_logf)
    return __builtin_amdgcn_logf(x);
#else
    float r; asm("v_log_f32 %0, %1" : "=v"(r) : "v"(x)); return r;
#endif
}

__device__ __forceinline__ unsigned short f2bf(float f) {
    union { float f; unsigned u; } v; v.f = f;
    unsigned r = v.u + 0x7FFFu + ((v.u >> 16) & 1u); // RNE
    return (unsigned short)(r >> 16);
}

// K1: row norms + positive dots + bf16 reps (pre-scaled by sqrt(C1)).
__global__ __launch_bounds__(256) void k_norm(const float* __restrict__ zi,
                                              const float* __restrict__ zj,
                                              unsigned* __restrict__ repsU,
                                              float* __restrict__ pos) {
    int w = threadIdx.x >> 6, lane = threadIdx.x & 63;
    int row = blockIdx.x * 4 + w;
    const float2* a2 = (const float2*)(zi + (size_t)row * D);
    const float2* b2 = (const float2*)(zj + (size_t)row * D);
    float2 a = a2[lane], b = b2[lane];
    float si = a.x * a.x + a.y * a.y;
    float sj = b.x * b.x + b.y * b.y;
    float sd = a.x * b.x + a.y * b.y;
#pragma unroll
    for (int m = 32; m; m >>= 1) {
        si += __shfl_xor(si, m);
        sj += __shfl_xor(sj, m);
        sd += __shfl_xor(sd, m);
    }
    float inv_i = 1.0f / fmaxf(sqrtf(si), 1e-12f);
    float inv_j = 1.0f / fmaxf(sqrtf(sj), 1e-12f);
    float sa = inv_i * RSCALE, sb = inv_j * RSCALE;
    repsU[(size_t)row * 64 + lane] =
        (unsigned)f2bf(a.x * sa) | ((unsigned)f2bf(a.y * sa) << 16);
    repsU[(size_t)(row + B_ROWS) * 64 + lane] =
        (unsigned)f2bf(b.x * sb) | ((unsigned)f2bf(b.y * sb) << 16);
    if (lane == 0) pos[row] = fast_exp2(sd * inv_i * inv_j * C1); // exp(2*cos_ij)
}

// K2: fused sim-GEMM + exp + row-sum, LDS double-buffered B panel.
// Per 64-col tile: 16x global_load_lds_dwordx4 (no VGPR cost, issued BEFORE
// compute of the current tile -> latency hidden under ~2500 cyc of MFMA).
// LDS is XOR-swizzled via pre-swizzled GLOBAL source + swizzled read offsets
// (rule #21): byte c of row r lives at c ^ ((r&7)<<4).
// C/D layout (m89-verified): row=(lane>>4)*4+q, col=lane&15.
__global__ __launch_bounds__(256, 2) void k_negsum(const unsigned short* __restrict__ R,
                                                   float* __restrict__ partial) {
    __shared__ char smem[2][TILE_BYTES];
    int js = blockIdx.x & (JSPLIT - 1);     // low bits -> js == XCD id (L2 locality)
    int rowBase = (blockIdx.x >> 3) * 256;
    int w = threadIdx.x >> 6;
    int lane = threadIdx.x & 63;
    int lr = lane & 15, lk = lane >> 4;
    int waveRow = rowBase + w * 64;

    bf16x8 afrag[4][4];
#pragma unroll
    for (int r = 0; r < 4; ++r)
#pragma unroll
        for (int kk = 0; kk < 4; ++kk)
            afrag[r][kk] = *(const bf16x8*)(R + (size_t)(waveRow + r * 16 + lr) * D + kk * 32 + lk * 8);

    // staging: instruction j of wave w covers dest bytes (w*4+j)*1024 + lane*16
    int srcoff[4], dstoff[4];
#pragma unroll
    for (int j = 0; j < 4; ++j) {
        int o = (w * 4 + j) * 1024 + lane * 16;
        int row = o >> 8, c = o & 255;
        srcoff[j] = row * 256 + (c ^ ((row & 7) << 4)); // pre-swizzled global source
        dstoff[j] = (w * 4 + j) * 1024;                 // wave-uniform LDS base
    }

    int colStart = js * COLS;
    const char* Rb = (const char*)R;
    int tdiag = (waveRow - colStart) >> 6;  // tile containing this wave's diagonal

    // swizzled read-offset components: lds_off(ct,kk) = ct*4096 + lbase + (kk*64 ^ m64)
    int m64 = (lr & 4) << 4;
    int lbase = lr * 256 + ((lk * 16) ^ ((lr & 3) << 4));

    float acc[4][4] = {};

#define STAGE(buf, t)                                                             \
    do {                                                                          \
        const char* tb_ = Rb + (size_t)(colStart + (t) * TILE_COLS) * 256;        \
        _Pragma("unroll")                                                         \
        for (int j = 0; j < 4; ++j)                                               \
            __builtin_amdgcn_global_load_lds(                                     \
                (const __attribute__((address_space(1))) unsigned*)(tb_ + srcoff[j]), \
                (__attribute__((address_space(3))) unsigned*)(&smem[buf][dstoff[j]]), \
                16, 0, 0);                                                        \
    } while (0)

#define BATCH_BODY(DIAG)                                                          \
    do {                                                                          \
        _Pragma("unroll")                                                         \
        for (int ct = 0; ct < 4; ++ct) {                                          \
            _Pragma("unroll")                                                     \
            for (int r = 0; r < 4; ++r) {                                         \
                f32x4 c = {0.f, 0.f, 0.f, 0.f};                                   \
                c = __builtin_amdgcn_mfma_f32_16x16x32_bf16(afrag[r][0], bf[ct][0], c, 0, 0, 0); \
                c = __builtin_amdgcn_mfma_f32_16x16x32_bf16(afrag[r][1], bf[ct][1], c, 0, 0, 0); \
                c = __builtin_amdgcn_mfma_f32_16x16x32_bf16(afrag[r][2], bf[ct][2], c, 0, 0, 0); \
                c = __builtin_amdgcn_mfma_f32_16x16x32_bf16(afrag[r][3], bf[ct][3], c, 0, 0, 0); \
                if (DIAG && ct == r) {                                            \
                    _Pragma("unroll")                                             \
                    for (int q = 0; q < 4; ++q)                                   \
                        if (lk * 4 + q != lr) acc[r][q] += fast_exp2(c[q]);       \
                } else {                                                          \
                    _Pragma("unroll")                                             \
                    for (int q = 0; q < 4; ++q) acc[r][q] += fast_exp2(c[q]);     \
                }                                                                 \
            }                                                                     \
        }                                                                         \
    } while (0)

    STAGE(0, 0);
    __syncthreads();                         // drains vmcnt(0) before first reads
    int cur = 0;
    for (int t = 0; t < NT; ++t) {
        if (t + 1 < NT) STAGE(cur ^ 1, t + 1);   // async prefetch, zero VGPR cost
        const char* sb = &smem[cur][0] + lbase;
        bf16x8 bf[4][4];
#pragma unroll
        for (int ct = 0; ct < 4; ++ct)
#pragma unroll
            for (int kk = 0; kk < 4; ++kk)
                bf[ct][kk] = *(const bf16x8*)(sb + ct * 4096 + ((kk * 64) ^ m64));
        if (t == tdiag) {
            BATCH_BODY(true);
        } else {
            BATCH_BODY(false);
        }
        __syncthreads();                     // orders buffer reuse + drains prefetch
        cur ^= 1;
    }
#undef STAGE
#undef BATCH_BODY

    // reduce the 16 col-lanes of each row group, write deterministic partials
#pragma unroll
    for (int r = 0; r < 4; ++r)
#pragma unroll
        for (int q = 0; q < 4; ++q) {
            float v = acc[r][q];
            v += __shfl_xor(v, 1);
            v += __shfl_xor(v, 2);
            v += __shfl_xor(v, 4);
            v += __shfl_xor(v, 8);
            if (lr == 0)
                partial[(size_t)js * NROWS + waveRow + r * 16 + lk * 4 + q] = v;
        }
}

// K3a: per-row loss terms + block partial sums. 64 blocks x 256 threads.
__global__ __launch_bounds__(256) void k_loss1(const float* __restrict__ pos,
                                               const float* __restrict__ partial,
                                               float* __restrict__ bsum) {
    int i = blockIdx.x * 256 + threadIdx.x;
    float neg = 0.f;
#pragma unroll
    for (int s = 0; s < JSPLIT; ++s) neg += partial[(size_t)s * NROWS + i];
    neg *= E_M2; // folded (sim - 2.0) shift
    float p = pos[i & (B_ROWS - 1)];
    float Ng = fmaxf((neg - 819.2f * p) * (1.0f / 0.9f), 8192.0f * E_M2);
    float l = fast_log2((p + Ng + 1e-8f) / p) * 0.69314718056f; // = -log(p/(p+Ng+eps))
#pragma unroll
    for (int m = 32; m; m >>= 1) l += __shfl_xor(l, m);
    __shared__ float s4[4];
    int wv = threadIdx.x >> 6;
    if ((threadIdx.x & 63) == 0) s4[wv] = l;
    __syncthreads();
    if (threadIdx.x == 0) bsum[blockIdx.x] = s4[0] + s4[1] + s4[2] + s4[3];
}

// K3b: final reduce of 64 block sums. 1 block, 1 wave.
__global__ void k_loss2(const float* __restrict__ bsum, float* __restrict__ out) {
    float v = bsum[threadIdx.x];
#pragma unroll
    for (int m = 32; m; m >>= 1) v += __shfl_xor(v, m);
    if (threadIdx.x == 0) out[0] = v * (1.0f / (float)NROWS);
}

extern "C" void kernel_launch(void* const* d_in, const int* in_sizes, int n_in,
                              void* d_out, int out_size, void* d_ws, size_t ws_size,
                              hipStream_t stream) {
    const float* zi = (const float*)d_in[0];
    const float* zj = (const float*)d_in[1];
    unsigned short* reps = (unsigned short*)d_ws;                    // 16384*128 bf16 = 4 MB
    float* pos = (float*)((char*)d_ws + (size_t)NROWS * D * 2);      // 8192 f32
    float* partial = pos + B_ROWS;                                   // 8*16384 f32
    float* bsum = partial + (size_t)JSPLIT * NROWS;                  // 64 f32
    float* out = (float*)d_out;

    k_norm<<<B_ROWS / 4, 256, 0, stream>>>(zi, zj, (unsigned*)reps, pos);
    k_negsum<<<64 * JSPLIT, 256, 0, stream>>>(reps, partial);
    k_loss1<<<NROWS / 256, 256, 0, stream>>>(pos, partial, bsum);
    k_loss2<<<1, 64, 0, stream>>>(bsum, out);
}